// Round 7
// baseline (5105.750 us; speedup 1.0000x reference)
//
#include <hip/hip_runtime.h>

// PhysicsRULModel fully-fused kernel for MI355X (gfx950).  R6.
// grid = 128 blocks x 512 threads; each block processes TWO batches (2b,2b+1).
// R6 rationale: R3/R4/R5 all land ~2100-2400 us despite very different
// VALU/LDS mixes -> latency-serialization-bound (serial per-step chain:
// ds_read -> dots -> QSUM -> exp/rcp act -> tanh -> write -> barrier, with
// nothing to overlap). Two independent batches per block share the weight
// VGPRs (still 96/lane) and fill each other's stall slots.
// Wave layout per R5: waves 0-3 h0-lanes (Whh0 i,f,g,o + Wih1 i,f quarter
// rows), waves 4-7 h1-lanes (Whh1 i,f,g,o + Wih1 g,o). Both batches' dots
// in each lane. h0s triple-buffered; g1ih passes Wih1(i,f) partials.
// Skews as R5: L0 step u at iter u; L1 step t=u-2; epilogue at u==2 (mod 16).

#define Bn 256
#define Tn 2048
#define Hn 64
#define CH 16
#define NT 512
#define NB 128   // grid blocks = Bn/2

typedef float f32x2 __attribute__((ext_vector_type(2)));

__device__ __forceinline__ float rcpf_(float x) { return __builtin_amdgcn_rcpf(x); }
__device__ __forceinline__ float tanhf2_(float x) {
    float e = __expf(2.0f * x);
    return 1.0f - 2.0f * rcpf_(e + 1.0f);
}
__device__ __forceinline__ void pkfma(f32x2& acc, f32x2 w, f32x2 x) {
    asm("v_pk_fma_f32 %0, %1, %2, %0" : "+v"(acc) : "v"(w), "v"(x));
}
#define DPPF(v, ctrl) __int_as_float(__builtin_amdgcn_update_dpp(0, __float_as_int(v), (ctrl), 0xF, 0xF, true))
#define QSUM(v) { v += DPPF(v, 0xB1); v += DPPF(v, 0x4E); }
#define DOT2(acc, w_, x_) { acc.x = fmaf((w_).x, (x_).x, acc.x); acc.y = fmaf((w_).y, (x_).y, acc.y); }

__device__ __forceinline__ float sel4_(float a0, float a1, float a2, float a3, int q) {
    float v = (q & 1) ? a1 : a0;
    float w = (q & 1) ? a3 : a2;
    return (q & 2) ? w : v;
}

__global__ __launch_bounds__(512, 2)
void fused_rul_kernel(
    const float* __restrict__ ts,   const float* __restrict__ sf,
    const float* __restrict__ Wih0, const float* __restrict__ Whh0,
    const float* __restrict__ bih0, const float* __restrict__ bhh0,
    const float* __restrict__ Wih1, const float* __restrict__ Whh1,
    const float* __restrict__ bih1, const float* __restrict__ bhh1,
    const float* __restrict__ seW1, const float* __restrict__ seb1,
    const float* __restrict__ seW2, const float* __restrict__ seb2,
    const float* __restrict__ pbW1, const float* __restrict__ pbb1,
    const float* __restrict__ pbW2, const float* __restrict__ pbb2,
    const float* __restrict__ pbW3, const float* __restrict__ pbb3,
    const float* __restrict__ drW1, const float* __restrict__ drb1,
    const float* __restrict__ drW2, const float* __restrict__ drb2,
    const float* __restrict__ drW3, const float* __restrict__ drb3,
    const float* __restrict__ ruW1, const float* __restrict__ rub1,
    const float* __restrict__ ruW2, const float* __restrict__ rub2,
    float* __restrict__ out)
{
    const int tid  = threadIdx.x;
    const int blk  = blockIdx.x;
    const int lane = tid & 63;
    const int w    = tid >> 6;
    const bool isH0 = (w < 4);
    const int q    = lane & 3;
    const int s    = ((w & 3) << 4) | (lane >> 2);

    // ---- LDS ----
    __shared__ __align__(16) float h0s[3][2][Hn];    // [slot][batch][unit]
    __shared__ __align__(16) float h1s[2][2][Hn];
    __shared__ __align__(16) float g1ih[2][2][Hn][2];
    __shared__ __align__(16) float h1ring[2][CH][Hn];
    __shared__ float tempc[2][CH];
    __shared__ __align__(16) float ssb[2][CH][32];
    __shared__ __align__(16) float se1b[2][CH][32];
    __shared__ __align__(16) float dr1b[2][CH][Hn];
    __shared__ float degb[2][CH];
    __shared__ float hltb[2][CH];
    __shared__ __align__(16) float seW1L[32 * 66];
    __shared__ __align__(16) float seW2L[32 * 34];
    __shared__ __align__(16) float drW1L[64 * 34];
    __shared__ __align__(8)  float drW1t[3][64];
    __shared__ __align__(16) float drW2L[32 * 66];
    __shared__ __align__(16) float ruW1L[32 * 34];
    __shared__ float ruW1t[32];
    __shared__ float seb1L[32], seb2L[32], drb1L[64], drb2L[32], drW3L[32];
    __shared__ float rub1L[32], ruW2L[32];
    __shared__ float phys_s[2][4];    // per batch: [A, -Ea*1000/R, Ea, logA]
    __shared__ float drb3_s, rub2_s;

    // ---- cooperative LDS weight staging ----
    for (int i = tid; i < 32 * 64; i += NT) { int rr = i >> 6, c = i & 63; seW1L[rr * 66 + c] = seW1[i]; }
    for (int i = tid; i < 32 * 32; i += NT) { int rr = i >> 5, c = i & 31; seW2L[rr * 34 + c] = seW2[i]; }
    for (int i = tid; i < 64 * 32; i += NT) { int rr = i >> 5, c = i & 31; drW1L[rr * 34 + c] = drW1[rr * 35 + c]; }
    if (tid < 192) { int k = tid >> 6, rr = tid & 63; drW1t[k][rr] = drW1[rr * 35 + 32 + k]; }
    for (int i = tid; i < 32 * 64; i += NT) { int rr = i >> 6, c = i & 63; drW2L[rr * 66 + c] = drW2[i]; }
    for (int i = tid; i < 32 * 32; i += NT) { int rr = i >> 5, c = i & 31; ruW1L[rr * 34 + c] = ruW1[rr * 33 + c]; }
    if (tid < 32) {
        ruW1t[tid] = ruW1[tid * 33 + 32];
        seb1L[tid] = seb1[tid]; seb2L[tid] = seb2[tid]; drb2L[tid] = drb2[tid];
        drW3L[tid] = drW3[tid]; rub1L[tid] = rub1[tid]; ruW2L[tid] = ruW2[tid];
    }
    if (tid < 64) drb1L[tid] = drb1[tid];
    if (tid == 0) { drb3_s = drb3[0]; rub2_s = rub2[0]; }

    // ---- physics branch: lanes 0,1 each handle one batch ----
    if (tid < 2) {
        const int bb = 2 * blk + tid;
        float p1[32];
        for (int o = 0; o < 32; ++o) {
            float a = pbb1[o];
            for (int k = 0; k < 3; ++k) a += pbW1[o * 3 + k] * sf[bb * 3 + k];
            p1[o] = fmaxf(a, 0.f);
        }
        float p2[16];
        for (int o = 0; o < 16; ++o) {
            float a = pbb2[o];
            for (int k = 0; k < 32; ++k) a += pbW2[o * 32 + k] * p1[k];
            p2[o] = fmaxf(a, 0.f);
        }
        float Ea = pbb3[0], lA = pbb3[1];
        for (int k = 0; k < 16; ++k) { Ea += pbW3[k] * p2[k]; lA += pbW3[16 + k] * p2[k]; }
        phys_s[tid][0] = __expf(lA);
        phys_s[tid][1] = -Ea * 1000.0f / 8.314f;
        phys_s[tid][2] = Ea;
        phys_s[tid][3] = lA;
    }

    // ---- LSTM weights into VGPRs (96 regs/lane, shared by both batches) ----
    f32x2 wA[32], wB[16];
    float bact, wi0a = 0.f, wi0b = 0.f;
    {
        const int rq = (q << 6) + s;
        const float* WAsrc = isH0 ? Whh0 : Whh1;
        const int gB0 = isH0 ? 0 : 2;
        #pragma unroll
        for (int g4 = 0; g4 < 4; ++g4) {
            const f32x2* pa = (const f32x2*)(WAsrc + ((g4 << 6) + s) * 64 + q * 16);
            #pragma unroll
            for (int k = 0; k < 8; ++k) wA[g4 * 8 + k] = pa[k];
        }
        #pragma unroll
        for (int g4 = 0; g4 < 2; ++g4) {
            const f32x2* pb = (const f32x2*)(Wih1 + (((gB0 + g4) << 6) + s) * 64 + q * 16);
            #pragma unroll
            for (int k = 0; k < 8; ++k) wB[g4 * 8 + k] = pb[k];
        }
        if (isH0) {
            bact = bih0[rq] + bhh0[rq];
            wi0a = Wih0[rq * 2 + 0]; wi0b = Wih0[rq * 2 + 1];
        } else {
            bact = bih1[rq] + bhh1[rq];
        }
    }
    const bool  isg  = (q == 2);
    const float kmul = isg ? 2.f : -1.f;
    const float kk   = isg ? -2.f : 1.f;
    const float cc   = isg ? 1.f : 0.f;

    float cstA = 0.f, cstB = 0.f;   // cell states per batch
    float hst = 1.0f;               // health state (lanes 0 and 32 use theirs)
    float xp1A = 0.f, xp2A = 0.f, xp1B = 0.f, xp2B = 0.f;
    if (tid < 128) {
        int bz = tid >> 6, uz = tid & 63;
        h0s[0][bz][uz] = 0.f; h0s[1][bz][uz] = 0.f; h0s[2][bz][uz] = 0.f;
        h1s[0][bz][uz] = 0.f; h1s[1][bz][uz] = 0.f;
    }
    __syncthreads();

    const float* tsbA = ts + (size_t)(2 * blk)     * Tn * 2;
    const float* tsbB = ts + (size_t)(2 * blk + 1) * Tn * 2;
    float* outR0 = out + (size_t)(2 * blk) * Tn;
    float* outR1 = out + (size_t)(2 * blk + 1) * Tn;
    float* outD0 = out + (size_t)Bn * Tn + (size_t)(2 * blk) * Tn;
    float* outD1 = out + (size_t)Bn * Tn + (size_t)(2 * blk + 1) * Tn;
    float* outH0 = out + 2 * (size_t)Bn * Tn + (size_t)(2 * blk) * Tn;
    float* outH1 = out + 2 * (size_t)Bn * Tn + (size_t)(2 * blk + 1) * Tn;

    int sW = 0, s1 = 2, s2 = 1;     // h0s rotating slots

    #pragma unroll 1
    for (int u = 0; u <= Tn + 2; ++u) {
        float2 xvA = make_float2(0.f, 0.f), xvB = make_float2(0.f, 0.f);
        if (isH0 && u < Tn) {
            xvA = *(const float2*)(tsbA + 2 * u);
            xvB = *(const float2*)(tsbB + 2 * u);
        }

        // ---------- epilogue for completed chunk ----------
        if ((u & (CH - 1)) == 2 && u >= 18) {
            const int t0 = u - 18;
            {   // se1 (both batches)
                const int pos = tid >> 5, jj = tid & 31;
                #pragma unroll
                for (int bt = 0; bt < 2; ++bt) {
                    float2 acc = make_float2(0.f, 0.f);
                    const float2* wr = (const float2*)(seW1L + jj * 66);
                    const float2* hr = (const float2*)(&h1ring[bt][pos][0]);
                    #pragma unroll
                    for (int k = 0; k < 32; ++k) { float2 ww = wr[k], hh = hr[k]; DOT2(acc, ww, hh); }
                    se1b[bt][pos][jj] = fmaxf(acc.x + acc.y + seb1L[jj], 0.f);
                }
            }
            __syncthreads();
            {   // se2
                const int pos = tid >> 5, jj = tid & 31;
                #pragma unroll
                for (int bt = 0; bt < 2; ++bt) {
                    float2 acc = make_float2(0.f, 0.f);
                    const float2* wr = (const float2*)(seW2L + jj * 34);
                    const float2* xr = (const float2*)(&se1b[bt][pos][0]);
                    #pragma unroll
                    for (int k = 0; k < 16; ++k) { float2 ww = wr[k], xx = xr[k]; DOT2(acc, ww, xx); }
                    ssb[bt][pos][jj] = acc.x + acc.y + seb2L[jj];
                }
            }
            __syncthreads();
            {   // dr1
                const int jj = tid & 63;
                const float2* wr = (const float2*)(drW1L + jj * 34);
                const float w32 = drW1t[0][jj], w33 = drW1t[1][jj], w34 = drW1t[2][jj];
                const float bb = drb1L[jj];
                #pragma unroll
                for (int bt = 0; bt < 2; ++bt) {
                    const float ea_ = phys_s[bt][2], la_ = phys_s[bt][3];
                    #pragma unroll
                    for (int rep = 0; rep < 2; ++rep) {
                        const int pos = (tid >> 6) + rep * 8;
                        float2 acc = make_float2(0.f, 0.f);
                        const float2* xr = (const float2*)(&ssb[bt][pos][0]);
                        #pragma unroll
                        for (int k = 0; k < 16; ++k) { float2 ww = wr[k], xx = xr[k]; DOT2(acc, ww, xx); }
                        float a = acc.x + acc.y + bb + w32 * tempc[bt][pos] + w33 * ea_ + w34 * la_;
                        dr1b[bt][pos][jj] = fmaxf(a, 0.f);
                    }
                }
            }
            __syncthreads();
            {   // dr2 + dr3 fused
                const int pos = tid >> 5, jj = tid & 31;
                #pragma unroll
                for (int bt = 0; bt < 2; ++bt) {
                    float2 acc = make_float2(0.f, 0.f);
                    const float2* wr = (const float2*)(drW2L + jj * 66);
                    const float2* xr = (const float2*)(&dr1b[bt][pos][0]);
                    #pragma unroll
                    for (int k = 0; k < 32; ++k) { float2 ww = wr[k], xx = xr[k]; DOT2(acc, ww, xx); }
                    float p = drW3L[jj] * fmaxf(acc.x + acc.y + drb2L[jj], 0.f);
                    #pragma unroll
                    for (int off = 16; off > 0; off >>= 1) p += __shfl_down(p, off, 32);
                    if (jj == 0) degb[bt][pos] = p + drb3_s;
                }
            }
            __syncthreads();
            if (tid == 0 || tid == 32) {   // health scans, one lane per batch
                const int bt = tid >> 5;
                const float Af = phys_s[bt][0], ne = phys_s[bt][1];
                float h_ = hst;
                #pragma unroll
                for (int p2 = 0; p2 < CH; ++p2) {
                    float tK  = tempc[bt][p2] + 273.15f;
                    float arr = Af * __expf(ne * rcpf_(tK));
                    float comb = 0.7f * degb[bt][p2] + 0.3f * arr;
                    h_ = fminf(fmaxf(h_ - comb, 0.f), 1.f);
                    hltb[bt][p2] = h_;
                }
                hst = h_;
            }
            __syncthreads();
            {   // rul head + outputs
                const int pos = tid >> 5, jj = tid & 31;
                #pragma unroll
                for (int bt = 0; bt < 2; ++bt) {
                    float2 acc = make_float2(0.f, 0.f);
                    const float2* wr = (const float2*)(ruW1L + jj * 34);
                    const float2* xr = (const float2*)(&ssb[bt][pos][0]);
                    #pragma unroll
                    for (int k = 0; k < 16; ++k) { float2 ww = wr[k], xx = xr[k]; DOT2(acc, ww, xx); }
                    float a = acc.x + acc.y + rub1L[jj] + ruW1t[jj] * hltb[bt][pos];
                    float p = ruW2L[jj] * fmaxf(a, 0.f);
                    #pragma unroll
                    for (int off = 16; off > 0; off >>= 1) p += __shfl_down(p, off, 32);
                    if (jj == 0) {
                        float* oR = bt ? outR1 : outR0;
                        oR[t0 + pos] = fmaxf(p + rub2_s, 0.f);
                    }
                }
            }
            if (tid < 2 * CH) {
                int bt = tid >> 4, p = tid & 15;
                (bt ? outD1 : outD0)[t0 + p] = degb[bt][p];
                (bt ? outH1 : outH0)[t0 + p] = hltb[bt][p];
            }
        }

        // ---------- LSTM step (both batches) ----------
        if (isH0) {
            if (u <= Tn) {
                const float4* hA = (const float4*)(&h0s[s1][0][q * 16]);
                const float4* hB = (const float4*)(&h0s[s1][1][q * 16]);
                f32x2 A0a={0,0},A1a={0,0},A2a={0,0},A3a={0,0},B0a={0,0},B1a={0,0};
                f32x2 A0b={0,0},A1b_={0,0},A2b={0,0},A3b={0,0},B0b={0,0},B1b={0,0};
                #pragma unroll
                for (int k = 0; k < 4; ++k) {
                    float4 a4 = hA[k], b4 = hB[k];
                    f32x2 alo = {a4.x, a4.y}, ahi = {a4.z, a4.w};
                    f32x2 blo = {b4.x, b4.y}, bhi = {b4.z, b4.w};
                    pkfma(A0a, wA[0 +2*k], alo); pkfma(A0a, wA[1 +2*k], ahi);
                    pkfma(A0b, wA[0 +2*k], blo); pkfma(A0b, wA[1 +2*k], bhi);
                    pkfma(A1a, wA[8 +2*k], alo); pkfma(A1a, wA[9 +2*k], ahi);
                    pkfma(A1b_, wA[8 +2*k], blo); pkfma(A1b_, wA[9 +2*k], bhi);
                    pkfma(A2a, wA[16+2*k], alo); pkfma(A2a, wA[17+2*k], ahi);
                    pkfma(A2b, wA[16+2*k], blo); pkfma(A2b, wA[17+2*k], bhi);
                    pkfma(A3a, wA[24+2*k], alo); pkfma(A3a, wA[25+2*k], ahi);
                    pkfma(A3b, wA[24+2*k], blo); pkfma(A3b, wA[25+2*k], bhi);
                    pkfma(B0a, wB[0 +2*k], alo); pkfma(B0a, wB[1 +2*k], ahi);
                    pkfma(B0b, wB[0 +2*k], blo); pkfma(B0b, wB[1 +2*k], bhi);
                    pkfma(B1a, wB[8 +2*k], alo); pkfma(B1a, wB[9 +2*k], ahi);
                    pkfma(B1b, wB[8 +2*k], blo); pkfma(B1b, wB[9 +2*k], bhi);
                }
                float Sa0A=A0a.x+A0a.y, Sa1A=A1a.x+A1a.y, Sa2A=A2a.x+A2a.y, Sa3A=A3a.x+A3a.y;
                float Sb0A=B0a.x+B0a.y, Sb1A=B1a.x+B1a.y;
                float Sa0B=A0b.x+A0b.y, Sa1B=A1b_.x+A1b_.y, Sa2B=A2b.x+A2b.y, Sa3B=A3b.x+A3b.y;
                float Sb0B=B0b.x+B0b.y, Sb1B=B1b.x+B1b.y;
                QSUM(Sa0A); QSUM(Sa1A); QSUM(Sa2A); QSUM(Sa3A); QSUM(Sb0A); QSUM(Sb1A);
                QSUM(Sa0B); QSUM(Sa1B); QSUM(Sa2B); QSUM(Sa3B); QSUM(Sb0B); QSUM(Sb1B);
                if (u < Tn) {
                    float valA = sel4_(Sa0A, Sa1A, Sa2A, Sa3A, q);
                    float valB = sel4_(Sa0B, Sa1B, Sa2B, Sa3B, q);
                    valA = fmaf(wi0a, xvA.x, fmaf(wi0b, xvA.y, valA + bact));
                    valB = fmaf(wi0a, xvB.x, fmaf(wi0b, xvB.y, valB + bact));
                    float actA = fmaf(rcpf_(1.f + __expf(kmul * valA)), kk, cc);
                    float actB = fmaf(rcpf_(1.f + __expf(kmul * valB)), kk, cc);
                    float giA = DPPF(actA,0x00), gfA = DPPF(actA,0x55), ggA = DPPF(actA,0xAA), goA = DPPF(actA,0xFF);
                    float giB = DPPF(actB,0x00), gfB = DPPF(actB,0x55), ggB = DPPF(actB,0xAA), goB = DPPF(actB,0xFF);
                    cstA = fmaf(gfA, cstA, giA * ggA);
                    cstB = fmaf(gfB, cstB, giB * ggB);
                    float h0nA = goA * tanhf2_(cstA);
                    float h0nB = goB * tanhf2_(cstB);
                    if (q == 0) { h0s[sW][0][s] = h0nA; h0s[sW][1][s] = h0nB; }
                }
                if (u >= 1 && q < 2) {
                    g1ih[u & 1][0][s][q] = (q == 1) ? Sb1A : Sb0A;
                    g1ih[u & 1][1][s][q] = (q == 1) ? Sb1B : Sb0B;
                }
            }
            if (tid == 0 && u >= 2 && u <= Tn + 1) {
                tempc[0][(u - 2) & (CH - 1)] = xp2A;
                tempc[1][(u - 2) & (CH - 1)] = xp2B;
            }
            xp2A = xp1A; xp1A = xvA.x;
            xp2B = xp1B; xp1B = xvB.x;
        } else {
            if (u >= 2 && u <= Tn + 1) {
                const float4* hA = (const float4*)(&h1s[(u + 1) & 1][0][q * 16]);
                const float4* hB = (const float4*)(&h1s[(u + 1) & 1][1][q * 16]);
                const float4* xA = (const float4*)(&h0s[s2][0][q * 16]);
                const float4* xB = (const float4*)(&h0s[s2][1][q * 16]);
                f32x2 A0a={0,0},A1a={0,0},A2a={0,0},A3a={0,0},B0a={0,0},B1a={0,0};
                f32x2 A0b={0,0},A1b_={0,0},A2b={0,0},A3b={0,0},B0b={0,0},B1b={0,0};
                #pragma unroll
                for (int k = 0; k < 4; ++k) {
                    float4 a4 = hA[k], b4 = hB[k];
                    f32x2 alo = {a4.x, a4.y}, ahi = {a4.z, a4.w};
                    f32x2 blo = {b4.x, b4.y}, bhi = {b4.z, b4.w};
                    pkfma(A0a, wA[0 +2*k], alo); pkfma(A0a, wA[1 +2*k], ahi);
                    pkfma(A0b, wA[0 +2*k], blo); pkfma(A0b, wA[1 +2*k], bhi);
                    pkfma(A1a, wA[8 +2*k], alo); pkfma(A1a, wA[9 +2*k], ahi);
                    pkfma(A1b_, wA[8 +2*k], blo); pkfma(A1b_, wA[9 +2*k], bhi);
                    pkfma(A2a, wA[16+2*k], alo); pkfma(A2a, wA[17+2*k], ahi);
                    pkfma(A2b, wA[16+2*k], blo); pkfma(A2b, wA[17+2*k], bhi);
                    pkfma(A3a, wA[24+2*k], alo); pkfma(A3a, wA[25+2*k], ahi);
                    pkfma(A3b, wA[24+2*k], blo); pkfma(A3b, wA[25+2*k], bhi);
                    float4 c4 = xA[k], d4 = xB[k];
                    f32x2 clo = {c4.x, c4.y}, chi = {c4.z, c4.w};
                    f32x2 dlo = {d4.x, d4.y}, dhi = {d4.z, d4.w};
                    pkfma(B0a, wB[0 +2*k], clo); pkfma(B0a, wB[1 +2*k], chi);
                    pkfma(B0b, wB[0 +2*k], dlo); pkfma(B0b, wB[1 +2*k], dhi);
                    pkfma(B1a, wB[8 +2*k], clo); pkfma(B1a, wB[9 +2*k], chi);
                    pkfma(B1b, wB[8 +2*k], dlo); pkfma(B1b, wB[9 +2*k], dhi);
                }
                float Sa0A=A0a.x+A0a.y, Sa1A=A1a.x+A1a.y, Sa2A=A2a.x+A2a.y, Sa3A=A3a.x+A3a.y;
                float Sb0A=B0a.x+B0a.y, Sb1A=B1a.x+B1a.y;
                float Sa0B=A0b.x+A0b.y, Sa1B=A1b_.x+A1b_.y, Sa2B=A2b.x+A2b.y, Sa3B=A3b.x+A3b.y;
                float Sb0B=B0b.x+B0b.y, Sb1B=B1b.x+B1b.y;
                QSUM(Sa0A); QSUM(Sa1A); QSUM(Sa2A); QSUM(Sa3A); QSUM(Sb0A); QSUM(Sb1A);
                QSUM(Sa0B); QSUM(Sa1B); QSUM(Sa2B); QSUM(Sa3B); QSUM(Sb0B); QSUM(Sb1B);
                float ptA = g1ih[(u - 1) & 1][0][s][q & 1];
                float ptB = g1ih[(u - 1) & 1][1][s][q & 1];
                float ihA = (q < 2) ? ptA : ((q == 2) ? Sb0A : Sb1A);
                float ihB = (q < 2) ? ptB : ((q == 2) ? Sb0B : Sb1B);
                float valA = sel4_(Sa0A, Sa1A, Sa2A, Sa3A, q) + ihA + bact;
                float valB = sel4_(Sa0B, Sa1B, Sa2B, Sa3B, q) + ihB + bact;
                float actA = fmaf(rcpf_(1.f + __expf(kmul * valA)), kk, cc);
                float actB = fmaf(rcpf_(1.f + __expf(kmul * valB)), kk, cc);
                float giA = DPPF(actA,0x00), gfA = DPPF(actA,0x55), ggA = DPPF(actA,0xAA), goA = DPPF(actA,0xFF);
                float giB = DPPF(actB,0x00), gfB = DPPF(actB,0x55), ggB = DPPF(actB,0xAA), goB = DPPF(actB,0xFF);
                cstA = fmaf(gfA, cstA, giA * ggA);
                cstB = fmaf(gfB, cstB, giB * ggB);
                float h1nA = goA * tanhf2_(cstA);
                float h1nB = goB * tanhf2_(cstB);
                if (q == 0) { h1s[u & 1][0][s] = h1nA; h1s[u & 1][1][s] = h1nB; }
                if (q == 1) { h1ring[0][(u - 2) & (CH - 1)][s] = h1nA; h1ring[1][(u - 2) & (CH - 1)][s] = h1nB; }
            }
        }
        int tmp = s2; s2 = s1; s1 = sW; sW = tmp;
        __syncthreads();
    }
}

extern "C" void kernel_launch(void* const* d_in, const int* in_sizes, int n_in,
                              void* d_out, int out_size, void* d_ws, size_t ws_size,
                              hipStream_t stream) {
    const float* ts   = (const float*)d_in[0];
    const float* sf   = (const float*)d_in[1];
    const float* Wih0 = (const float*)d_in[2];
    const float* Whh0 = (const float*)d_in[3];
    const float* bih0 = (const float*)d_in[4];
    const float* bhh0 = (const float*)d_in[5];
    const float* Wih1 = (const float*)d_in[6];
    const float* Whh1 = (const float*)d_in[7];
    const float* bih1 = (const float*)d_in[8];
    const float* bhh1 = (const float*)d_in[9];
    const float* seW1 = (const float*)d_in[10];
    const float* seb1 = (const float*)d_in[11];
    const float* seW2 = (const float*)d_in[12];
    const float* seb2 = (const float*)d_in[13];
    const float* pbW1 = (const float*)d_in[14];
    const float* pbb1 = (const float*)d_in[15];
    const float* pbW2 = (const float*)d_in[16];
    const float* pbb2 = (const float*)d_in[17];
    const float* pbW3 = (const float*)d_in[18];
    const float* pbb3 = (const float*)d_in[19];
    const float* drW1 = (const float*)d_in[20];
    const float* drb1 = (const float*)d_in[21];
    const float* drW2 = (const float*)d_in[22];
    const float* drb2 = (const float*)d_in[23];
    const float* drW3 = (const float*)d_in[24];
    const float* drb3 = (const float*)d_in[25];
    const float* ruW1 = (const float*)d_in[26];
    const float* rub1 = (const float*)d_in[27];
    const float* ruW2 = (const float*)d_in[28];
    const float* rub2 = (const float*)d_in[29];
    float* out = (float*)d_out;

    fused_rul_kernel<<<dim3(NB), dim3(NT), 0, stream>>>(
        ts, sf, Wih0, Whh0, bih0, bhh0, Wih1, Whh1, bih1, bhh1,
        seW1, seb1, seW2, seb2, pbW1, pbb1, pbW2, pbb2, pbW3, pbb3,
        drW1, drb1, drW2, drb2, drW3, drb3, ruW1, rub1, ruW2, rub2, out);
}

// Round 8
// 1915.626 us; speedup vs baseline: 2.6653x; 2.6653x over previous
//
#include <hip/hip_runtime.h>

// PhysicsRULModel fully-fused kernel for MI355X (gfx950).  R7.
// grid = 256 x 512 (1 block/CU, 8 waves). LSTM identical to R5 (best: 2053us).
// R7 attacks the LDS-issue pipe (the real bottleneck: ~1700 cyc/step of LDS
// ops, ~60% in the epilogue):
//  - CH=32; epilogue positions owned per-wave (wave w: {w, w+8, w+16, w+24});
//    stage weights loaded ONCE per epilogue into registers (b128, pitches
//    68/36 -> 16B-aligned rows); acts read as b128 broadcasts; intermediates
//    wave-private -> epilogue barriers 6 -> 2 (around health only).
//  - health scan parallelized as a clamp-affine scan (clip(h+a,l,u) composes
//    closed-form) on wave 0: 5 shfl_up steps vs 32-step serial exp chain.
//  - __launch_bounds__(512,1): 2nd arg is minBlocks on this compiler; =2
//    capped VGPR at 128 and spilled (R4/R6 WRITE_SIZE blowups). =1 -> cap 256.
// Ring-slot safety: t0 === 0 (mod 32) so ring slot == pos; the pre-health
// barrier guarantees all ring reads (stages A/B) complete before any wave
// reaches the LSTM writes of this iteration.

#define Bn 256
#define Tn 2048
#define Hn 64
#define CH 32
#define NT 512

typedef float f32x2 __attribute__((ext_vector_type(2)));

__device__ __forceinline__ float rcpf_(float x) { return __builtin_amdgcn_rcpf(x); }
__device__ __forceinline__ float tanhf2_(float x) {
    float e = __expf(2.0f * x);
    return 1.0f - 2.0f * rcpf_(e + 1.0f);
}
__device__ __forceinline__ void pkfma(f32x2& acc, f32x2 w, f32x2 x) {
    asm("v_pk_fma_f32 %0, %1, %2, %0" : "+v"(acc) : "v"(w), "v"(x));
}
#define DPPF(v, ctrl) __int_as_float(__builtin_amdgcn_update_dpp(0, __float_as_int(v), (ctrl), 0xF, 0xF, true))
#define QSUM(v) { v += DPPF(v, 0xB1); v += DPPF(v, 0x4E); }
#define DOT4(acc, w_, x_) { acc = fmaf((w_).x,(x_).x, fmaf((w_).y,(x_).y, fmaf((w_).z,(x_).z, fmaf((w_).w,(x_).w, acc)))); }
#define LGKM0() asm volatile("s_waitcnt lgkmcnt(0)" ::: "memory")

__device__ __forceinline__ float sel4_(float a0, float a1, float a2, float a3, int q) {
    float v = (q & 1) ? a1 : a0;
    float w = (q & 1) ? a3 : a2;
    return (q & 2) ? w : v;
}
// full-wave sum (64 lanes): quad DPP xor1,2 + shfl_xor 4,8,16,32
__device__ __forceinline__ float wsum64_(float v) {
    v += DPPF(v, 0xB1); v += DPPF(v, 0x4E);
    v += __shfl_xor(v, 4); v += __shfl_xor(v, 8);
    v += __shfl_xor(v, 16); v += __shfl_xor(v, 32);
    return v;
}

__global__ __launch_bounds__(512, 1)
void fused_rul_kernel(
    const float* __restrict__ ts,   const float* __restrict__ sf,
    const float* __restrict__ Wih0, const float* __restrict__ Whh0,
    const float* __restrict__ bih0, const float* __restrict__ bhh0,
    const float* __restrict__ Wih1, const float* __restrict__ Whh1,
    const float* __restrict__ bih1, const float* __restrict__ bhh1,
    const float* __restrict__ seW1, const float* __restrict__ seb1,
    const float* __restrict__ seW2, const float* __restrict__ seb2,
    const float* __restrict__ pbW1, const float* __restrict__ pbb1,
    const float* __restrict__ pbW2, const float* __restrict__ pbb2,
    const float* __restrict__ pbW3, const float* __restrict__ pbb3,
    const float* __restrict__ drW1, const float* __restrict__ drb1,
    const float* __restrict__ drW2, const float* __restrict__ drb2,
    const float* __restrict__ drW3, const float* __restrict__ drb3,
    const float* __restrict__ ruW1, const float* __restrict__ rub1,
    const float* __restrict__ ruW2, const float* __restrict__ rub2,
    float* __restrict__ out)
{
    const int tid  = threadIdx.x;
    const int b    = blockIdx.x;
    const int lane = tid & 63;
    const int w    = tid >> 6;          // wave 0..7
    const bool isH0 = (w < 4);
    const int q    = lane & 3;          // quarter (cols 16q..16q+15)
    const int s    = ((w & 3) << 4) | (lane >> 2);   // unit 0..63

    // ---- LDS ----
    __shared__ __align__(16) float h0s[3][Hn];       // triple-buffered (R5)
    __shared__ __align__(16) float h1s[2][Hn];
    __shared__ __align__(16) float g1ih[2][Hn][2];   // L1 ih partials (i,f)
    __shared__ __align__(16) float h1ring[CH][Hn];   // slot = t & 31
    __shared__ float tempc[CH];
    __shared__ __align__(16) float ssb[CH][32];      // system_states per chunk
    __shared__ __align__(16) float se1b[8][32];      // wave-private
    __shared__ __align__(16) float dr1b[8][Hn];      // wave-private
    __shared__ float degb[CH];
    __shared__ float hltb[CH];
    // MLP weights: b128-aligned pitches (68, 36)
    __shared__ __align__(16) float seW1L[32 * 68];
    __shared__ __align__(16) float seW2L[32 * 36];
    __shared__ __align__(16) float drW1L[64 * 36];   // cols 0..34 (incl tails)
    __shared__ __align__(16) float drW2L[32 * 68];
    __shared__ __align__(16) float ruW1L[32 * 36];   // cols 0..32 (incl health)
    __shared__ float seb1L[32], seb2L[32], drb1L[64], drb2L[32], drW3L[32];
    __shared__ float rub1L[32], ruW2L[32];
    __shared__ float phys_s[4];       // [A, -Ea*1000/R, Ea, logA]
    __shared__ float drb3_s, rub2_s;

    // ---- cooperative LDS weight staging ----
    for (int i = tid; i < 32 * 64; i += NT) { int rr = i >> 6, c = i & 63; seW1L[rr * 68 + c] = seW1[i]; }
    for (int i = tid; i < 32 * 32; i += NT) { int rr = i >> 5, c = i & 31; seW2L[rr * 36 + c] = seW2[i]; }
    for (int i = tid; i < 64 * 35; i += NT) { int rr = i / 35, c = i % 35; drW1L[rr * 36 + c] = drW1[i]; }
    for (int i = tid; i < 32 * 64; i += NT) { int rr = i >> 6, c = i & 63; drW2L[rr * 68 + c] = drW2[i]; }
    for (int i = tid; i < 32 * 33; i += NT) { int rr = i / 33, c = i % 33; ruW1L[rr * 36 + c] = ruW1[i]; }
    if (tid < 32) {
        seb1L[tid] = seb1[tid]; seb2L[tid] = seb2[tid]; drb2L[tid] = drb2[tid];
        drW3L[tid] = drW3[tid]; rub1L[tid] = rub1[tid]; ruW2L[tid] = ruW2[tid];
    }
    if (tid < 64) drb1L[tid] = drb1[tid];
    if (tid == 0) { drb3_s = drb3[0]; rub2_s = rub2[0]; }

    // ---- physics branch (tiny MLP, thread 0) ----
    if (tid == 0) {
        float p1[32];
        for (int o = 0; o < 32; ++o) {
            float a = pbb1[o];
            for (int k = 0; k < 3; ++k) a += pbW1[o * 3 + k] * sf[b * 3 + k];
            p1[o] = fmaxf(a, 0.f);
        }
        float p2[16];
        for (int o = 0; o < 16; ++o) {
            float a = pbb2[o];
            for (int k = 0; k < 32; ++k) a += pbW2[o * 32 + k] * p1[k];
            p2[o] = fmaxf(a, 0.f);
        }
        float Ea = pbb3[0], lA = pbb3[1];
        for (int k = 0; k < 16; ++k) { Ea += pbW3[k] * p2[k]; lA += pbW3[16 + k] * p2[k]; }
        phys_s[0] = __expf(lA);
        phys_s[1] = -Ea * 1000.0f / 8.314f;
        phys_s[2] = Ea;
        phys_s[3] = lA;
    }

    // ---- LSTM weights into VGPRs (96/lane, exactly as R5) ----
    f32x2 wA[32], wB[16];
    float bact, wi0a = 0.f, wi0b = 0.f;
    {
        const int rq = (q << 6) + s;
        const float* WAsrc = isH0 ? Whh0 : Whh1;
        const int gB0 = isH0 ? 0 : 2;
        #pragma unroll
        for (int g4 = 0; g4 < 4; ++g4) {
            const f32x2* pa = (const f32x2*)(WAsrc + ((g4 << 6) + s) * 64 + q * 16);
            #pragma unroll
            for (int k = 0; k < 8; ++k) wA[g4 * 8 + k] = pa[k];
        }
        #pragma unroll
        for (int g4 = 0; g4 < 2; ++g4) {
            const f32x2* pb = (const f32x2*)(Wih1 + (((gB0 + g4) << 6) + s) * 64 + q * 16);
            #pragma unroll
            for (int k = 0; k < 8; ++k) wB[g4 * 8 + k] = pb[k];
        }
        if (isH0) {
            bact = bih0[rq] + bhh0[rq];
            wi0a = Wih0[rq * 2 + 0]; wi0b = Wih0[rq * 2 + 1];
        } else {
            bact = bih1[rq] + bhh1[rq];
        }
    }
    const bool  isg  = (q == 2);
    const float kmul = isg ? 2.f : -1.f;
    const float kk   = isg ? -2.f : 1.f;
    const float cc   = isg ? 1.f : 0.f;

    float cst = 0.f;
    float hst = 1.0f;               // valid on wave 0 lanes
    float xprev = 0.f, xprev2 = 0.f;
    if (tid < 64) {
        h0s[0][tid] = 0.f; h0s[1][tid] = 0.f; h0s[2][tid] = 0.f;
        h1s[0][tid] = 0.f; h1s[1][tid] = 0.f;
    }
    __syncthreads();

    const float* tsb  = ts + (size_t)b * Tn * 2;
    float* outR = out + (size_t)b * Tn;
    float* outD = out + (size_t)Bn * Tn + (size_t)b * Tn;
    float* outH = out + 2 * (size_t)Bn * Tn + (size_t)b * Tn;

    int sW = 0, s1 = 2, s2 = 1;     // h0s rotating slots

    #pragma unroll 1
    for (int u = 0; u <= Tn + 2; ++u) {
        float2 xv = make_float2(0.f, 0.f);
        if (isH0 && u < Tn) xv = *(const float2*)(tsb + 2 * u);

        // ================= epilogue: chunk [u-34, u-3], pos ring slot == pos ==========
        if ((u & (CH - 1)) == 2 && u >= 34) {
            const int t0 = u - 34;
            const int hh = (tid >> 5) & 1;    // half within wave
            const int jj = tid & 31;
            const int j64 = lane;

            // ---- Stage A: se1 + se2 (wave-private), 4 positions ----
            {
                float4 w1[8], w2[4];
                const float4* p1 = (const float4*)(seW1L + jj * 68 + hh * 32);
                #pragma unroll
                for (int k = 0; k < 8; ++k) w1[k] = p1[k];
                const float4* p2 = (const float4*)(seW2L + jj * 36 + hh * 16);
                #pragma unroll
                for (int k = 0; k < 4; ++k) w2[k] = p2[k];
                const float b1 = seb1L[jj], b2 = seb2L[jj];
                #pragma unroll
                for (int i = 0; i < 4; ++i) {
                    const int pos = w + 8 * i;
                    const float4* ha = (const float4*)(&h1ring[pos][hh * 32]);
                    float acc = 0.f;
                    #pragma unroll
                    for (int k = 0; k < 8; ++k) { float4 hv = ha[k]; DOT4(acc, w1[k], hv); }
                    acc += __shfl_xor(acc, 32);
                    float se1v = fmaxf(acc + b1, 0.f);
                    if (hh == 0) se1b[w][jj] = se1v;
                    LGKM0();
                    const float4* sa = (const float4*)(&se1b[w][hh * 16]);
                    float a2 = 0.f;
                    #pragma unroll
                    for (int k = 0; k < 4; ++k) { float4 xv4 = sa[k]; DOT4(a2, w2[k], xv4); }
                    a2 += __shfl_xor(a2, 32);
                    if (hh == 0) ssb[pos][jj] = a2 + b2;
                }
            }
            LGKM0();
            // ---- Stage B: dr1 + dr2 + dr3 (wave-private), 4 positions ----
            {
                float4 wd1[9];
                const float4* p1 = (const float4*)(drW1L + j64 * 36);
                #pragma unroll
                for (int k = 0; k < 9; ++k) wd1[k] = p1[k];
                float4 wd2[8];
                const float4* p2 = (const float4*)(drW2L + jj * 68 + hh * 32);
                #pragma unroll
                for (int k = 0; k < 8; ++k) wd2[k] = p2[k];
                const float bb1 = drb1L[j64], bb2 = drb2L[jj], w3 = drW3L[jj];
                const float ea_ = phys_s[2], la_ = phys_s[3];
                #pragma unroll
                for (int i = 0; i < 4; ++i) {
                    const int pos = w + 8 * i;
                    const float tmp_ = tempc[pos];
                    const float4* xa = (const float4*)(&ssb[pos][0]);
                    float acc = 0.f;
                    #pragma unroll
                    for (int k = 0; k < 8; ++k) { float4 xv4 = xa[k]; DOT4(acc, wd1[k], xv4); }
                    acc += wd1[8].x * tmp_ + wd1[8].y * ea_ + wd1[8].z * la_;
                    dr1b[w][j64] = fmaxf(acc + bb1, 0.f);
                    LGKM0();
                    const float4* da = (const float4*)(&dr1b[w][hh * 32]);
                    float a2 = 0.f;
                    #pragma unroll
                    for (int k = 0; k < 8; ++k) { float4 xv4 = da[k]; DOT4(a2, wd2[k], xv4); }
                    a2 += __shfl_xor(a2, 32);
                    float tt = w3 * fmaxf(a2 + bb2, 0.f);
                    float sum = wsum64_(tt);              // each jj counted twice
                    float deg = 0.5f * sum + drb3_s;
                    if (lane == 0) { degb[pos] = deg; outD[t0 + pos] = deg; }
                }
            }
            __syncthreads();
            // ---- Stage C: health scan (wave 0, parallel clamp-affine scan) ----
            if (w == 0) {
                const int t = lane;
                const float Af = phys_s[0], ne = phys_s[1];
                float a_ = 0.f, l_ = -1e30f, u_ = 1e30f;
                if (t < 32) {
                    float dg = degb[t];
                    float tK = tempc[t] + 273.15f;
                    float arr = Af * __expf(ne * rcpf_(tK));
                    a_ = -(0.7f * dg + 0.3f * arr);
                    l_ = 0.f; u_ = 1.f;
                }
                #pragma unroll
                for (int d = 1; d < 32; d <<= 1) {
                    float pa = __shfl_up(a_, d);
                    float pl = __shfl_up(l_, d);
                    float pu = __shfl_up(u_, d);
                    if (t >= d && t < 32) {
                        float na = pa + a_;
                        float nl = fminf(fmaxf(pl + a_, l_), u_);
                        float nu = fminf(fmaxf(pu + a_, l_), u_);
                        a_ = na; l_ = nl; u_ = nu;
                    }
                }
                float hval = fminf(fmaxf(hst + a_, l_), u_);
                if (t < 32) { hltb[t] = hval; outH[t0 + t] = hval; }
                float a31 = __shfl(a_, 31), l31 = __shfl(l_, 31), u31 = __shfl(u_, 31);
                hst = fminf(fmaxf(hst + a31, l31), u31);
            }
            __syncthreads();
            // ---- Stage D: rul head, 4 positions ----
            {
                float4 wr4[4];
                const float4* p1 = (const float4*)(ruW1L + jj * 36 + hh * 16);
                #pragma unroll
                for (int k = 0; k < 4; ++k) wr4[k] = p1[k];
                const float whc = ruW1L[jj * 36 + 32];
                const float br = rub1L[jj], w2r = ruW2L[jj];
                #pragma unroll
                for (int i = 0; i < 4; ++i) {
                    const int pos = w + 8 * i;
                    const float4* xa = (const float4*)(&ssb[pos][hh * 16]);
                    float acc = 0.f;
                    #pragma unroll
                    for (int k = 0; k < 4; ++k) { float4 xv4 = xa[k]; DOT4(acc, wr4[k], xv4); }
                    acc += __shfl_xor(acc, 32);
                    float aa = acc + br + whc * hltb[pos];
                    float pp = w2r * fmaxf(aa, 0.f);
                    float sum = wsum64_(pp);
                    if (lane == 0) outR[t0 + pos] = fmaxf(0.5f * sum + rub2_s, 0.f);
                }
            }
        }

        // ================= LSTM step (exactly R5) =================
        if (isH0) {
            if (u <= Tn) {
                const float4* hv4 = (const float4*)(&h0s[s1][q * 16]);
                f32x2 A0 = {0,0}, A1 = {0,0}, A2 = {0,0}, A3 = {0,0}, B0 = {0,0}, B1 = {0,0};
                #pragma unroll
                for (int k = 0; k < 4; ++k) {
                    float4 h4 = hv4[k];
                    f32x2 lo = {h4.x, h4.y}, hi = {h4.z, h4.w};
                    pkfma(A0, wA[0  + 2*k], lo); pkfma(A0, wA[1  + 2*k], hi);
                    pkfma(A1, wA[8  + 2*k], lo); pkfma(A1, wA[9  + 2*k], hi);
                    pkfma(A2, wA[16 + 2*k], lo); pkfma(A2, wA[17 + 2*k], hi);
                    pkfma(A3, wA[24 + 2*k], lo); pkfma(A3, wA[25 + 2*k], hi);
                    pkfma(B0, wB[0  + 2*k], lo); pkfma(B0, wB[1  + 2*k], hi);
                    pkfma(B1, wB[8  + 2*k], lo); pkfma(B1, wB[9  + 2*k], hi);
                }
                float Sa0 = A0.x + A0.y, Sa1 = A1.x + A1.y, Sa2 = A2.x + A2.y, Sa3 = A3.x + A3.y;
                float Sb0 = B0.x + B0.y, Sb1 = B1.x + B1.y;
                QSUM(Sa0); QSUM(Sa1); QSUM(Sa2); QSUM(Sa3);
                QSUM(Sb0); QSUM(Sb1);
                if (u < Tn) {
                    float val = sel4_(Sa0, Sa1, Sa2, Sa3, q);
                    val = fmaf(wi0a, xv.x, fmaf(wi0b, xv.y, val + bact));
                    float act = fmaf(rcpf_(1.f + __expf(kmul * val)), kk, cc);
                    float gi = DPPF(act, 0x00), gf = DPPF(act, 0x55), gg = DPPF(act, 0xAA), go = DPPF(act, 0xFF);
                    cst = fmaf(gf, cst, gi * gg);
                    float h0new = go * tanhf2_(cst);
                    if (q == 0) h0s[sW][s] = h0new;
                }
                if (u >= 1 && q < 2) {
                    float ptv = (q == 1) ? Sb1 : Sb0;
                    g1ih[u & 1][s][q] = ptv;
                }
            }
            if (tid == 0 && u >= 2 && u <= Tn + 1) tempc[(u - 2) & (CH - 1)] = xprev2;
            xprev2 = xprev; xprev = xv.x;
        } else {
            if (u >= 2 && u <= Tn + 1) {
                const float4* hv4 = (const float4*)(&h1s[(u + 1) & 1][q * 16]);
                const float4* xv4p = (const float4*)(&h0s[s2][q * 16]);
                f32x2 A0 = {0,0}, A1 = {0,0}, A2 = {0,0}, A3 = {0,0}, B0 = {0,0}, B1 = {0,0};
                #pragma unroll
                for (int k = 0; k < 4; ++k) {
                    float4 h4 = hv4[k];
                    f32x2 lo = {h4.x, h4.y}, hi = {h4.z, h4.w};
                    pkfma(A0, wA[0  + 2*k], lo); pkfma(A0, wA[1  + 2*k], hi);
                    pkfma(A1, wA[8  + 2*k], lo); pkfma(A1, wA[9  + 2*k], hi);
                    pkfma(A2, wA[16 + 2*k], lo); pkfma(A2, wA[17 + 2*k], hi);
                    pkfma(A3, wA[24 + 2*k], lo); pkfma(A3, wA[25 + 2*k], hi);
                    float4 x4 = xv4p[k];
                    f32x2 xlo = {x4.x, x4.y}, xhi = {x4.z, x4.w};
                    pkfma(B0, wB[0  + 2*k], xlo); pkfma(B0, wB[1  + 2*k], xhi);
                    pkfma(B1, wB[8  + 2*k], xlo); pkfma(B1, wB[9  + 2*k], xhi);
                }
                float Sa0 = A0.x + A0.y, Sa1 = A1.x + A1.y, Sa2 = A2.x + A2.y, Sa3 = A3.x + A3.y;
                float Sb0 = B0.x + B0.y, Sb1 = B1.x + B1.y;
                QSUM(Sa0); QSUM(Sa1); QSUM(Sa2); QSUM(Sa3);
                QSUM(Sb0); QSUM(Sb1);
                float ptl = g1ih[(u - 1) & 1][s][q & 1];
                float ihq = (q < 2) ? ptl : ((q == 2) ? Sb0 : Sb1);
                float val = sel4_(Sa0, Sa1, Sa2, Sa3, q) + ihq + bact;
                float act = fmaf(rcpf_(1.f + __expf(kmul * val)), kk, cc);
                float gi = DPPF(act, 0x00), gf = DPPF(act, 0x55), gg = DPPF(act, 0xAA), go = DPPF(act, 0xFF);
                cst = fmaf(gf, cst, gi * gg);
                float h1new = go * tanhf2_(cst);
                if (q == 0) h1s[u & 1][s] = h1new;
                if (q == 1) h1ring[(u - 2) & (CH - 1)][s] = h1new;
            }
        }
        int tmp = s2; s2 = s1; s1 = sW; sW = tmp;
        __syncthreads();
    }
}

extern "C" void kernel_launch(void* const* d_in, const int* in_sizes, int n_in,
                              void* d_out, int out_size, void* d_ws, size_t ws_size,
                              hipStream_t stream) {
    const float* ts   = (const float*)d_in[0];
    const float* sf   = (const float*)d_in[1];
    const float* Wih0 = (const float*)d_in[2];
    const float* Whh0 = (const float*)d_in[3];
    const float* bih0 = (const float*)d_in[4];
    const float* bhh0 = (const float*)d_in[5];
    const float* Wih1 = (const float*)d_in[6];
    const float* Whh1 = (const float*)d_in[7];
    const float* bih1 = (const float*)d_in[8];
    const float* bhh1 = (const float*)d_in[9];
    const float* seW1 = (const float*)d_in[10];
    const float* seb1 = (const float*)d_in[11];
    const float* seW2 = (const float*)d_in[12];
    const float* seb2 = (const float*)d_in[13];
    const float* pbW1 = (const float*)d_in[14];
    const float* pbb1 = (const float*)d_in[15];
    const float* pbW2 = (const float*)d_in[16];
    const float* pbb2 = (const float*)d_in[17];
    const float* pbW3 = (const float*)d_in[18];
    const float* pbb3 = (const float*)d_in[19];
    const float* drW1 = (const float*)d_in[20];
    const float* drb1 = (const float*)d_in[21];
    const float* drW2 = (const float*)d_in[22];
    const float* drb2 = (const float*)d_in[23];
    const float* drW3 = (const float*)d_in[24];
    const float* drb3 = (const float*)d_in[25];
    const float* ruW1 = (const float*)d_in[26];
    const float* rub1 = (const float*)d_in[27];
    const float* ruW2 = (const float*)d_in[28];
    const float* rub2 = (const float*)d_in[29];
    float* out = (float*)d_out;

    fused_rul_kernel<<<dim3(Bn), dim3(NT), 0, stream>>>(
        ts, sf, Wih0, Whh0, bih0, bhh0, Wih1, Whh1, bih1, bhh1,
        seW1, seb1, seW2, seb2, pbW1, pbb1, pbW2, pbb2, pbW3, pbb3,
        drW1, drb1, drW2, drb2, drW3, drb3, ruW1, rub1, ruW2, rub2, out);
}